// Round 11
// baseline (400.107 us; speedup 1.0000x reference)
//
#include <hip/hip_runtime.h>

// ConvMlp4d: conv4d(64->128) + bias + relu -> conv4d(128->64) + bias.
// R11 root-cause fix: FETCH_SIZE 73MB vs 18MB ideal == weights evicted from
// per-XCD L2 by the A-DMA/output streams and re-fetched from HBM (~900cyc) ->
// the loop-shape-invariant ~1000cyc/group stall that pinned every round at
// ~160us/conv. Changes: (a) A-DMA marked non-temporal (aux=2) + NT stores for
// conv2's dead fp32 output -> B stays L2-resident; (b) register double-buffered
// (ks,kw) groups (loads lead MFMAs by ~384cyc); (c) fully-coalesced cvt_x;
// (d) conv2 = 128-thr blocks, grid 1024 (4-6 blocks/CU vs R10's 2).
//   ws: x_t bf16 [2][65536][64] | h_t bf16 [2][65536][128] (chunk-planar:
//       [nb][tu][v][chunk=c/8][w][c%8])
//       w1t bf16 [81][4][128][16] | w2t bf16 [81][8][64][16]

using bf16x8 = __attribute__((ext_vector_type(8))) __bf16;
using f32x16 = __attribute__((ext_vector_type(16))) float;
using f32x4  = __attribute__((ext_vector_type(4))) float;

typedef __attribute__((address_space(1))) const void as1_void;
typedef __attribute__((address_space(3))) void as3_void;
__device__ __forceinline__ void gload_lds16_nt(const void* g, void* l) {
    __builtin_amdgcn_global_load_lds((as1_void*)g, (as3_void*)l, 16, 0, 2); // nt
}

// ------- prep: x (2,64,65536) f32 -> x_t chunk-planar bf16, fully coalesced --------
__global__ __launch_bounds__(256) void cvt_x(const float* __restrict__ x,
                                             __bf16* __restrict__ x_t) {
    const int idx = blockIdx.x * 256 + threadIdx.x;   // 2*65536*8 threads
    const int w  = idx & 31;
    const int g  = (idx >> 5) & 7;                    // chunk
    const int v  = (idx >> 8) & 31;
    const int tu = (idx >> 13) & 63;
    const int nb = idx >> 19;
    const int p  = tu * 1024 + v * 32 + w;
    const float* src = x + ((size_t)(nb * 64 + g * 8)) * 65536 + p;
    bf16x8 o;
    #pragma unroll
    for (int j = 0; j < 8; ++j)
        o[j] = (__bf16)src[(size_t)j * 65536];        // each read coalesced over w
    *(bf16x8*)(x_t + (size_t)(nb * 2048 + tu * 32 + v) * 2048 + g * 256 + w * 8) = o;
}

// ------- prep: w (O,CIN,81) f32 -> wt [81][CIN/16][COUT][16] bf16 ------------------
template <int CIN>
__global__ __launch_bounds__(256) void cvt_w(const float* __restrict__ w,
                                             __bf16* __restrict__ wt) {
    constexpr int COUT = 8192 / CIN;
    constexpr int LOGC = (CIN == 64) ? 7 : 6;   // log2(COUT)
    const int tap = blockIdx.x;                 // 0..80
    __bf16* dst = wt + (size_t)tap * 8192;
    #pragma unroll
    for (int it = 0; it < 32; ++it) {
        const int i  = it * 256 + threadIdx.x;  // kg*(COUT*16) + o*16 + cl
        const int cl = i & 15;
        const int o  = (i >> 4) & (COUT - 1);
        const int kg = i >> (4 + LOGC);
        dst[i] = (__bf16)w[(size_t)(o * CIN + kg * 16 + cl) * 81 + tap];
    }
}

// ---------------- fused conv4d (implicit GEMM, 32x32x16 bf16 MFMA) -----------------
// Block = WAVES waves, wave tile M=128 (rr=4, kv-reuse af[6]) x N=32. Block tile
// M=128 (v-span 4), N=WAVES*32. Staging unit = (kt,ku) x 32ch: LDS
// [row6][chunk4][wp34] x 16B = 13056 B, ping-pong 26112 B. K-loop: waitcnt +
// barrier; issue NT-DMA(i+1); compute(i) with register-double-buffered groups.
template <int CIN, int COUT, int WAVES, bool RELU>
__global__ __launch_bounds__(WAVES * 64, 3) void conv4d_mfma(
    const __bf16* __restrict__ in_t,   // chunk-planar activations
    const __bf16* __restrict__ wt,     // [81][CIN/16][COUT][16]
    const float* __restrict__ bias,    // [COUT]
    __bf16* __restrict__ out_bf,       // chunk-planar (RELU path)
    float* __restrict__ out_f)         // [2][COUT][65536]  (else)
{
    constexpr int KST     = CIN / 16;
    constexpr int UNITS   = CIN / 32;
    constexpr int LOGU    = (UNITS == 2) ? 1 : 2;
    constexpr int THREADS = WAVES * 64;
    constexpr int SLOTS   = 6 * 136;                 // 816 16B slots per unit
    constexpr int RNDS    = (SLOTS + THREADS - 1) / THREADS;
    constexpr int BUFB    = SLOTS * 16;              // 13056 B

    __shared__ __bf16 tile[2 * SLOTS * 8];           // 26112 B ping-pong

    const int tid  = threadIdx.x;
    const int lane = tid & 63;
    const int l31  = lane & 31;
    const int hl   = lane >> 5;
    const int wv   = tid >> 6;
    const int gni  = wv;                             // N wave index

    // grid: xcd(3b) | ulo(1b) | vg(3b) | t(2b) | nb(1b); u = xcd*2+ulo -> 1024
    const int bid = blockIdx.x;
    const int xcd = bid & 7;
    const int s0  = bid >> 3;
    const int u   = xcd * 2 + (s0 & 1);
    const int vg  = (s0 >> 1) & 7;
    const int t   = (s0 >> 4) & 3;
    const int nb  = (s0 >> 6) & 1;
    const int v0  = vg * 4;
    const int pbase = ((t * 16 + u) * 32 + v0) * 32;

    const __bf16* inb = in_t + (size_t)nb * 65536 * CIN;

    // ---- per-lane staging offsets (slot = r*THREADS + tid), chunk-planar ----
    int goff[RNDS];
    #pragma unroll
    for (int r = 0; r < RNDS; ++r) {
        const int slot = r * THREADS + tid;
        const int row  = slot / 136;                 // LDS [row6][chunk4][wp34]
        const int rem  = slot - row * 136;
        const int chunk = rem / 34;
        const int wp   = rem - chunk * 34;
        const int v_in = v0 - 1 + row;
        const int w_in = wp - 1;
        const bool ok = (slot < SLOTS) && ((unsigned)v_in < 32u) &&
                        ((unsigned)w_in < 32u);
        goff[r] = ok ? (v_in * (CIN * 32) + chunk * 256 + w_in * 8) : -1;
    }

    // ---- one-time zero pre-fill of invalid slots (both buffers) ----
    #pragma unroll
    for (int r = 0; r < RNDS; ++r) {
        const int slot = r * THREADS + tid;
        if (slot < SLOTS && goff[r] < 0) {
            *(uint4*)((char*)tile + slot * 16) = make_uint4(0u, 0u, 0u, 0u);
            *(uint4*)((char*)tile + BUFB + slot * 16) = make_uint4(0u, 0u, 0u, 0u);
        }
    }

    // A-read lane base (16B slots): slot = row*136 + (ks*2+hl)*34 + l31 + kw
    const int lane_base = hl * 34 + l31;
    const bf16x8* tile16 = (const bf16x8*)tile;

    // B lane pointer: o = gni*32 + l31; + hl*8 within the 16-ch group
    const __bf16* wlane = wt + ((size_t)(gni * 32 + l31)) * 16 + hl * 8;

    // ---- valid (kt,ku) stage list (block-uniform) ----
    int sb[9], tb0[9], nst = 0;
    #pragma unroll
    for (int kt = 0; kt < 3; ++kt) {
        const int t_in = t + kt - 1;
        if ((unsigned)t_in >= 4u) continue;
        #pragma unroll
        for (int ku = 0; ku < 3; ++ku) {
            const int u_in = u + ku - 1;
            if ((unsigned)u_in >= 16u) continue;
            sb[nst]  = (t_in * 16 + u_in) * 1024 * CIN;
            tb0[nst] = (kt * 3 + ku) * 9;
            ++nst;
        }
    }
    const int U = nst * UNITS;

    f32x16 acc[4];
    #pragma unroll
    for (int mt = 0; mt < 4; ++mt)
        #pragma unroll
        for (int i = 0; i < 16; ++i)
            acc[mt][i] = 0.f;

    // DMA issue for unit j (exec-masked; NT so the stream doesn't evict B)
    auto issue = [&](int j) {
        const int st = j >> LOGU, ch = j & (UNITS - 1);
        const __bf16* gb = inb + sb[st] + ch * 1024;   // unit = 4 chunk-planes
        char* lb = ((char*)tile) + (j & 1) * BUFB + wv * 1024;
        #pragma unroll
        for (int r = 0; r < RNDS; ++r)
            if (goff[r] >= 0)
                gload_lds16_nt(gb + goff[r], lb + r * (THREADS * 16));
    };

    issue(0);
    #pragma unroll 1
    for (int i = 0; i < U; ++i) {
        // Forced drain: DMA(i) was issued a full unit of compute ago (i>0).
        asm volatile("s_waitcnt vmcnt(0) lgkmcnt(0)" ::: "memory");
        __syncthreads();
        if (i + 1 < U) issue(i + 1);

        const int st = i >> LOGU, ch = i & (UNITS - 1);
        const int tapb = tb0[st];
        const bf16x8* tb = tile16 + (i & 1) * SLOTS + lane_base;

        bf16x8 af[2][6], bv[2][3];
        // preload group 0 (ks=0, kw=0)
        #pragma unroll
        for (int j = 0; j < 6; ++j) af[0][j] = tb[j * 136];
        #pragma unroll
        for (int kv = 0; kv < 3; ++kv)
            bv[0][kv] = *(const bf16x8*)(wlane +
                        ((tapb + kv * 3) * KST + ch * 2) * (COUT * 16));

        #pragma unroll
        for (int g = 0; g < 6; ++g) {
            const int cur = g & 1, nxt = cur ^ 1;
            if (g < 5) {                      // load group g+1 ahead of MFMAs
                const int gn = g + 1, ksn = gn / 3, kwn = gn % 3;
                #pragma unroll
                for (int j = 0; j < 6; ++j)
                    af[nxt][j] = tb[j * 136 + ksn * 68 + kwn];
                #pragma unroll
                for (int kv = 0; kv < 3; ++kv)
                    bv[nxt][kv] = *(const bf16x8*)(wlane +
                        ((tapb + kv * 3 + kwn) * KST + ch * 2 + ksn) * (COUT * 16));
            }
            #pragma unroll
            for (int kv = 0; kv < 3; ++kv)
                #pragma unroll
                for (int rr = 0; rr < 4; ++rr)
                    acc[rr] = __builtin_amdgcn_mfma_f32_32x32x16_bf16(
                        af[cur][rr + kv], bv[cur][kv], acc[rr], 0, 0, 0);
        }
    }

    // ---- epilogue: C/D 32x32: col = lane&31, row = (reg&3) + 8*(reg>>2) + 4*hl ----
    {
        const int o = gni * 32 + l31;
        const float bvls = bias[o];
        #pragma unroll
        for (int rr = 0; rr < 4; ++rr) {
            const int pb = pbase + rr * 32;
            if constexpr (RELU) {
                #pragma unroll
                for (int rg = 0; rg < 4; ++rg)
                    #pragma unroll
                    for (int j = 0; j < 4; ++j) {
                        float v = acc[rr][rg * 4 + j] + bvls;
                        v = v > 0.f ? v : 0.f;
                        const int p = pb + j + 8 * rg + 4 * hl;
                        const int vv = (p >> 5) & 31, ww = p & 31, tu = p >> 10;
                        out_bf[(size_t)nb * 65536 * COUT +
                               (size_t)(tu * 32 + vv) * (32 * COUT) +
                               (o >> 3) * 256 + ww * 8 + (o & 7)] = (__bf16)v;
                    }
            } else {
                #pragma unroll
                for (int rg = 0; rg < 4; ++rg) {
                    f32x4 sv;
                    #pragma unroll
                    for (int j = 0; j < 4; ++j)
                        sv[j] = acc[rr][rg * 4 + j] + bvls;
                    const int p = pb + 8 * rg + 4 * hl;
                    // dead-stream output: NT store, keep L2 for weights
                    __builtin_nontemporal_store(sv,
                        (f32x4*)(out_f + ((size_t)nb * COUT + o) * 65536 + p));
                }
            }
        }
    }
}

extern "C" void kernel_launch(void* const* d_in, const int* in_sizes, int n_in,
                              void* d_out, int out_size, void* d_ws, size_t ws_size,
                              hipStream_t stream) {
    const float* x  = (const float*)d_in[0];
    const float* w1 = (const float*)d_in[1];
    const float* b1 = (const float*)d_in[2];
    const float* w2 = (const float*)d_in[3];
    const float* b2 = (const float*)d_in[4];
    float* out = (float*)d_out;

    char* ws = (char*)d_ws;
    __bf16* x_t = (__bf16*)ws;                               // 16,777,216 B
    __bf16* h_t = (__bf16*)(ws + 16777216);                  // 33,554,432 B
    __bf16* w1t = (__bf16*)(ws + 50331648);                  //  1,327,104 B
    __bf16* w2t = (__bf16*)(ws + 51658752);                  //  1,327,104 B

    cvt_x<<<4096, 256, 0, stream>>>(x, x_t);
    cvt_w<64><<<81, 256, 0, stream>>>(w1, w1t);
    cvt_w<128><<<81, 256, 0, stream>>>(w2, w2t);

    // conv1: 4 waves (N=128), v-span 4, grid 1024, relu -> chunk-planar h_t
    conv4d_mfma<64, 128, 4, true><<<1024, 256, 0, stream>>>(x_t, w1t, b1, h_t,
                                                            nullptr);
    // conv2: 2 waves (N=64), v-span 4, grid 1024, fp32 planar out (NT stores)
    conv4d_mfma<128, 64, 2, false><<<1024, 128, 0, stream>>>(h_t, w2t, b2, nullptr,
                                                             out);
}